// Round 1
// baseline (3783.994 us; speedup 1.0000x reference)
//
#include <hip/hip_runtime.h>
#include <math.h>

#define Nn 10000
#define Ee 160000
#define NPB 40            // dst nodes per block
#define NBLK 250          // 250 * 40 = 10000
#define NKER 125
#define NBUCK (NBLK * NKER)
#define KCHUNK 32         // k-range per grid.y slice (4 slices: 32,32,32,29)

// ---------------------------------------------------------------- basis
__global__ __launch_bounds__(256) void basis_kernel(const float* __restrict__ pseudo,
                                                    float* __restrict__ bw,
                                                    int* __restrict__ fl)
{
    int e = blockIdx.x * 256 + threadIdx.x;
    if (e >= Ee) return;
    float p0 = pseudo[e * 3 + 0] * 4.f;
    float p1 = pseudo[e * 3 + 1] * 4.f;
    float p2 = pseudo[e * 3 + 2] * 4.f;
    float f0 = floorf(p0), f1 = floorf(p1), f2 = floorf(p2);
    float fr0 = p0 - f0, fr1 = p1 - f1, fr2 = p2 - f2;
    int lo0 = (int)f0; lo0 = lo0 < 0 ? 0 : (lo0 > 4 ? 4 : lo0);
    int lo1 = (int)f1; lo1 = lo1 < 0 ? 0 : (lo1 > 4 ? 4 : lo1);
    int lo2 = (int)f2; lo2 = lo2 < 0 ? 0 : (lo2 > 4 ? 4 : lo2);
    int hi0 = lo0 + 1 > 4 ? 4 : lo0 + 1;
    int hi1 = lo1 + 1 > 4 ? 4 : lo1 + 1;
    int hi2 = lo2 + 1 > 4 ? 4 : lo2 + 1;
#pragma unroll
    for (int s = 0; s < 8; ++s) {
        int c0 = (s >> 2) & 1, c1 = (s >> 1) & 1, c2 = s & 1;
        float b = (c0 ? fr0 : 1.f - fr0) * (c1 ? fr1 : 1.f - fr1) * (c2 ? fr2 : 1.f - fr2);
        int f = (c0 ? hi0 : lo0) + 5 * (c1 ? hi1 : lo1) + 25 * (c2 ? hi2 : lo2);
        bw[e * 8 + s] = b;
        fl[e * 8 + s] = f;
    }
}

// ---------------------------------------------------------------- degree
__global__ __launch_bounds__(256) void deg_kernel(const int* __restrict__ dst, int* __restrict__ degi)
{
    int e = blockIdx.x * 256 + threadIdx.x;
    if (e >= Ee) return;
    atomicAdd(&degi[dst[e]], 1);
}

__global__ __launch_bounds__(256) void invdeg_kernel(const int* __restrict__ degi, float* __restrict__ invdeg)
{
    int n = blockIdx.x * 256 + threadIdx.x;
    if (n >= Nn) return;
    int d = degi[n];
    invdeg[n] = 1.f / (float)(d > 0 ? d : 1);
}

// ---------------------------------------------------------------- pair sort (counting sort by (dstblock, k))
__global__ __launch_bounds__(256) void hist_kernel(const int* __restrict__ dst, const int* __restrict__ fl,
                                                   int* __restrict__ hist)
{
    int t = blockIdx.x * 256 + threadIdx.x;
    if (t >= Ee * 8) return;
    int e = t >> 3;
    int key = (dst[e] / NPB) * NKER + fl[t];
    atomicAdd(&hist[key], 1);
}

__global__ __launch_bounds__(1024) void scan_kernel(const int* __restrict__ hist, int* __restrict__ boff)
{
    const int T = 1024;
    const int per = (NBUCK + T - 1) / T;   // 31
    int t = threadIdx.x;
    int beg = t * per;
    int end = beg + per; if (end > NBUCK) end = NBUCK;
    int s = 0;
    for (int i = beg; i < end && i < NBUCK; ++i) s += hist[i];
    __shared__ int tmp[1024];
    tmp[t] = s;
    __syncthreads();
    for (int o2 = 1; o2 < 1024; o2 <<= 1) {
        int v = (t >= o2) ? tmp[t - o2] : 0;
        __syncthreads();
        tmp[t] += v;
        __syncthreads();
    }
    int run = tmp[t] - s;   // exclusive prefix for this thread's range
    for (int i = beg; i < end && i < NBUCK; ++i) { boff[i] = run; run += hist[i]; }
    if (t == T - 1) boff[NBUCK] = run;
}

__global__ __launch_bounds__(256) void fill_kernel(const int* __restrict__ srcA, const int* __restrict__ dstA,
                                                   const float* __restrict__ bw, const int* __restrict__ fl,
                                                   int* __restrict__ cursor, uint2* __restrict__ recs)
{
    int t = blockIdx.x * 256 + threadIdx.x;
    if (t >= Ee * 8) return;
    int e = t >> 3;
    int d = dstA[e];
    int key = (d / NPB) * NKER + fl[t];
    int pos = atomicAdd(&cursor[key], 1);
    unsigned meta = (unsigned)srcA[e] | ((unsigned)(d % NPB) << 16);
    recs[pos] = make_uint2(meta, __float_as_uint(bw[t]));
}

// ---------------------------------------------------------------- spline conv core
// grid (NBLK, ceil(125/KCHUNK)); one workgroup aggregates into its dst-block's LDS slab.
template <int CIN, int COUT>
__global__ __launch_bounds__(256) void conv_pairs_kernel(const uint2* __restrict__ recs,
                                                         const int* __restrict__ boff,
                                                         const float* __restrict__ xin,
                                                         const float* __restrict__ W,
                                                         float* __restrict__ agg)
{
    __shared__ float aggl[NPB * COUT];
    const int blk = blockIdx.x;
    for (int idx = threadIdx.x; idx < NPB * COUT; idx += 256) aggl[idx] = 0.f;
    __syncthreads();

    const int lane = threadIdx.x & 63;
    const int wid  = threadIdx.x >> 6;
    const int o    = lane;

    int k0 = blockIdx.y * KCHUNK;
    int k1 = k0 + KCHUNK; if (k1 > NKER) k1 = NKER;

    for (int k = k0; k < k1; ++k) {
        int bidx = blk * NKER + k;
        int pb = boff[bidx], pe = boff[bidx + 1];
        if (pb >= pe) continue;
        // register-resident W[k] column o
        float wreg[CIN];
#pragma unroll
        for (int i = 0; i < CIN; ++i)
            wreg[i] = (o < COUT) ? W[(k * CIN + i) * COUT + o] : 0.f;

        for (int p = pb + wid; p < pe; p += 4) {
            uint2 r = recs[p];
            unsigned meta = (unsigned)__builtin_amdgcn_readfirstlane((int)r.x);
            float wt = __uint_as_float(r.y);
            int src = (int)(meta & 0xFFFFu);
            int dl  = (int)(meta >> 16);
            const float* xs = xin + src * CIN;
            float m0 = 0.f, m1 = 0.f, m2 = 0.f, m3 = 0.f;
            if (CIN >= 4) {
#pragma unroll
                for (int i = 0; i < CIN; i += 4) {
                    m0 += xs[i + 0] * wreg[i + 0];
                    m1 += xs[i + 1] * wreg[i + 1];
                    m2 += xs[i + 2] * wreg[i + 2];
                    m3 += xs[i + 3] * wreg[i + 3];
                }
            } else {
#pragma unroll
                for (int i = 0; i < CIN; ++i) m0 += xs[i] * wreg[i];
            }
            float m = (m0 + m1) + (m2 + m3);
            if (o < COUT) atomicAdd(&aggl[dl * COUT + o], wt * m);
        }
    }
    __syncthreads();
    for (int idx = threadIdx.x; idx < NPB * COUT; idx += 256) {
        int n = blk * NPB + idx / COUT;
        if (n < Nn) atomicAdd(&agg[n * COUT + (idx % COUT)], aggl[idx]);
    }
}

// ---------------------------------------------------------------- conv epilogue: /deg + root + bias + elu
template <int CIN, int COUT>
__global__ __launch_bounds__(256) void epilogue_kernel(const float* __restrict__ agg,
                                                       const float* __restrict__ xin,
                                                       const float* __restrict__ root,
                                                       const float* __restrict__ bias,
                                                       const float* __restrict__ invdeg,
                                                       float* __restrict__ out)
{
    int idx = blockIdx.x * 256 + threadIdx.x;
    int n = idx / COUT, o = idx % COUT;
    if (n >= Nn) return;
    float r0 = 0.f, r1 = 0.f;
#pragma unroll
    for (int i = 0; i < CIN; i += 2) {
        r0 += xin[n * CIN + i] * root[i * COUT + o];
        if (CIN > 1) r1 += xin[n * CIN + i + 1] * root[(i + 1) * COUT + o];
    }
    float v = agg[n * COUT + o] * invdeg[n] + r0 + r1 + bias[o];
    out[n * COUT + o] = v > 0.f ? v : expm1f(v);
}

// ---------------------------------------------------------------- lin1: 64 -> 256, elu
__global__ __launch_bounds__(256) void lin1_kernel(const float* __restrict__ h,
                                                   const float* __restrict__ w1,
                                                   const float* __restrict__ b1,
                                                   float* __restrict__ out)
{
    int n = blockIdx.x;
    __shared__ float hl[64];
    if (threadIdx.x < 64) hl[threadIdx.x] = h[n * 64 + threadIdx.x];
    __syncthreads();
    int j = threadIdx.x;
    float a0 = b1[j], a1 = 0.f, a2 = 0.f, a3 = 0.f;
#pragma unroll
    for (int i = 0; i < 64; i += 4) {
        a0 += hl[i + 0] * w1[(i + 0) * 256 + j];
        a1 += hl[i + 1] * w1[(i + 1) * 256 + j];
        a2 += hl[i + 2] * w1[(i + 2) * 256 + j];
        a3 += hl[i + 3] * w1[(i + 3) * 256 + j];
    }
    float acc = (a0 + a1) + (a2 + a3);
    out[n * 256 + j] = acc > 0.f ? acc : expm1f(acc);
}

// ---------------------------------------------------------------- lin2: 256 -> 6890 (logits)
#define LNT 32
__global__ __launch_bounds__(256) void lin2_kernel(const float* __restrict__ h,
                                                   const float* __restrict__ w2,
                                                   const float* __restrict__ b2,
                                                   float* __restrict__ out)
{
    __shared__ float hT[256 * LNT];   // [i][n]
    int n0 = blockIdx.x * LNT;
    int j0 = blockIdx.y * 1024;
    for (int idx = threadIdx.x; idx < 256 * LNT; idx += 256) {
        int i = idx & 255, nl = idx >> 8;
        hT[i * LNT + nl] = (n0 + nl < Nn) ? h[(n0 + nl) * 256 + i] : 0.f;
    }
    __syncthreads();

    int j[4];
#pragma unroll
    for (int c = 0; c < 4; ++c) j[c] = j0 + (int)threadIdx.x + 256 * c;

    float acc[4][LNT];
#pragma unroll
    for (int c = 0; c < 4; ++c)
#pragma unroll
        for (int nl = 0; nl < LNT; ++nl) acc[c][nl] = 0.f;

    for (int i = 0; i < 256; ++i) {
        float wv[4];
#pragma unroll
        for (int c = 0; c < 4; ++c)
            wv[c] = (j[c] < 6890) ? w2[i * 6890 + j[c]] : 0.f;
        const float4* hp = (const float4*)&hT[i * LNT];
#pragma unroll
        for (int q = 0; q < LNT / 4; ++q) {
            float4 h4 = hp[q];
#pragma unroll
            for (int c = 0; c < 4; ++c) {
                acc[c][q * 4 + 0] += wv[c] * h4.x;
                acc[c][q * 4 + 1] += wv[c] * h4.y;
                acc[c][q * 4 + 2] += wv[c] * h4.z;
                acc[c][q * 4 + 3] += wv[c] * h4.w;
            }
        }
    }
#pragma unroll
    for (int c = 0; c < 4; ++c) {
        if (j[c] >= 6890) continue;
        float bb = b2[j[c]];
        for (int nl = 0; nl < LNT; ++nl) {
            int n = n0 + nl;
            if (n < Nn) out[(size_t)n * 6890 + j[c]] = acc[c][nl] + bb;
        }
    }
}

// ---------------------------------------------------------------- log_softmax (in place over d_out rows)
__global__ __launch_bounds__(1024) void lsm_kernel(float* __restrict__ out)
{
    int row = blockIdx.x;
    float* p = out + (size_t)row * 6890;
    __shared__ float red[16];
    int tid = threadIdx.x, lane = tid & 63, wid = tid >> 6;

    float m = -3.4e38f;
    for (int jj = tid; jj < 6890; jj += 1024) m = fmaxf(m, p[jj]);
#pragma unroll
    for (int off = 32; off > 0; off >>= 1) m = fmaxf(m, __shfl_down(m, off));
    if (lane == 0) red[wid] = m;
    __syncthreads();
    if (tid == 0) {
        float mm = red[0];
        for (int w = 1; w < 16; ++w) mm = fmaxf(mm, red[w]);
        red[0] = mm;
    }
    __syncthreads();
    m = red[0];
    __syncthreads();

    float s = 0.f;
    for (int jj = tid; jj < 6890; jj += 1024) s += expf(p[jj] - m);
#pragma unroll
    for (int off = 32; off > 0; off >>= 1) s += __shfl_down(s, off);
    if (lane == 0) red[wid] = s;
    __syncthreads();
    if (tid == 0) {
        float ss = 0.f;
        for (int w = 1; w < 16; ++w) ss += red[w];
        red[0] += ss;
    }
    __syncthreads();
    float lse = m + logf(red[0]);
    for (int jj = tid; jj < 6890; jj += 1024) p[jj] -= lse;
}

// ---------------------------------------------------------------- launch
extern "C" void kernel_launch(void* const* d_in, const int* in_sizes, int n_in,
                              void* d_out, int out_size, void* d_ws, size_t ws_size,
                              hipStream_t stream)
{
    const float* x      = (const float*)d_in[0];
    const int*   ei     = (const int*)d_in[1];
    const float* pseudo = (const float*)d_in[2];
    const float* W1     = (const float*)d_in[3];
    const float* root1  = (const float*)d_in[4];
    const float* b1     = (const float*)d_in[5];
    const float* W2     = (const float*)d_in[6];
    const float* root2  = (const float*)d_in[7];
    const float* b2     = (const float*)d_in[8];
    const float* Ws     = (const float*)d_in[9];
    const float* roots  = (const float*)d_in[10];
    const float* bs     = (const float*)d_in[11];
    const float* l1w    = (const float*)d_in[12];
    const float* l1b    = (const float*)d_in[13];
    const float* l2w    = (const float*)d_in[14];
    const float* l2b    = (const float*)d_in[15];
    float* out = (float*)d_out;

    const int* srcA = ei;
    const int* dstA = ei + Ee;

    char* base = (char*)d_ws;
    size_t off = 0;
    auto carve = [&](size_t bytes) -> void* {
        void* p = base + off;
        off += (bytes + 255) & ~(size_t)255;
        return p;
    };
    float* bw     = (float*)carve((size_t)Ee * 8 * 4);
    int*   fl     = (int*)carve((size_t)Ee * 8 * 4);
    int*   hist   = (int*)carve((size_t)NBUCK * 4);
    int*   boff   = (int*)carve((size_t)(NBUCK + 1) * 4);
    int*   cursor = (int*)carve((size_t)NBUCK * 4);
    uint2* recs   = (uint2*)carve((size_t)Ee * 8 * 8);
    int*   degi   = (int*)carve((size_t)Nn * 4);
    float* invdeg = (float*)carve((size_t)Nn * 4);
    float* agg    = (float*)carve((size_t)Nn * 64 * 4);
    float* hA     = (float*)carve((size_t)Nn * 64 * 4);
    float* hB     = (float*)carve((size_t)Nn * 64 * 4);
    float* h256   = (float*)carve((size_t)Nn * 256 * 4);
    (void)ws_size; (void)n_in; (void)in_sizes; (void)out_size;

    hipMemsetAsync(hist, 0, (size_t)NBUCK * 4, stream);
    hipMemsetAsync(degi, 0, (size_t)Nn * 4, stream);

    basis_kernel<<<(Ee + 255) / 256, 256, 0, stream>>>(pseudo, bw, fl);
    deg_kernel<<<(Ee + 255) / 256, 256, 0, stream>>>(dstA, degi);
    invdeg_kernel<<<(Nn + 255) / 256, 256, 0, stream>>>(degi, invdeg);
    hist_kernel<<<(Ee * 8 + 255) / 256, 256, 0, stream>>>(dstA, fl, hist);
    scan_kernel<<<1, 1024, 0, stream>>>(hist, boff);
    hipMemcpyAsync(cursor, boff, (size_t)NBUCK * 4, hipMemcpyDeviceToDevice, stream);
    fill_kernel<<<(Ee * 8 + 255) / 256, 256, 0, stream>>>(srcA, dstA, bw, fl, cursor, recs);

    const dim3 cgrid(NBLK, (NKER + KCHUNK - 1) / KCHUNK);

    // layer 1: 1 -> 32
    hipMemsetAsync(agg, 0, (size_t)Nn * 64 * 4, stream);
    conv_pairs_kernel<1, 32><<<cgrid, 256, 0, stream>>>(recs, boff, x, W1, agg);
    epilogue_kernel<1, 32><<<(Nn * 32 + 255) / 256, 256, 0, stream>>>(agg, x, root1, b1, invdeg, hA);

    // layer 2: 32 -> 64
    hipMemsetAsync(agg, 0, (size_t)Nn * 64 * 4, stream);
    conv_pairs_kernel<32, 64><<<cgrid, 256, 0, stream>>>(recs, boff, hA, W2, agg);
    epilogue_kernel<32, 64><<<(Nn * 64 + 255) / 256, 256, 0, stream>>>(agg, hA, root2, b2, invdeg, hB);

    // layers 3..6: 64 -> 64
    float* cin = hB;
    float* cot = hA;
    for (int l = 0; l < 4; ++l) {
        hipMemsetAsync(agg, 0, (size_t)Nn * 64 * 4, stream);
        conv_pairs_kernel<64, 64><<<cgrid, 256, 0, stream>>>(recs, boff, cin, Ws + (size_t)l * 125 * 64 * 64, agg);
        epilogue_kernel<64, 64><<<(Nn * 64 + 255) / 256, 256, 0, stream>>>(
            agg, cin, roots + (size_t)l * 64 * 64, bs + (size_t)l * 64, invdeg, cot);
        float* t = cin; cin = cot; cot = t;
    }

    lin1_kernel<<<Nn, 256, 0, stream>>>(cin, l1w, l1b, h256);
    lin2_kernel<<<dim3((Nn + LNT - 1) / LNT, 7), 256, 0, stream>>>(h256, l2w, l2b, out);
    lsm_kernel<<<Nn, 1024, 0, stream>>>(out);
}

// Round 2
// 3482.788 us; speedup vs baseline: 1.0865x; 1.0865x over previous
//
#include <hip/hip_runtime.h>
#include <hip/hip_bf16.h>
#include <math.h>

#define Nn 10000
#define Ee 160000
#define NPB 40            // dst nodes per block
#define NBLK 250          // 250 * 40 = 10000
#define NKER 125
#define NBUCK (NBLK * NKER)
#define KCHUNK 32         // k-range per grid.y slice (4 slices: 32,32,32,29)

#define MPAD 10048        // 157 * 64
#define NPAD 6912         // 54 * 128
#define NCLS 6890

typedef short bf16x8 __attribute__((ext_vector_type(8)));
typedef float f32x4  __attribute__((ext_vector_type(4)));

// ---------------------------------------------------------------- basis
__global__ __launch_bounds__(256) void basis_kernel(const float* __restrict__ pseudo,
                                                    float* __restrict__ bw,
                                                    int* __restrict__ fl)
{
    int e = blockIdx.x * 256 + threadIdx.x;
    if (e >= Ee) return;
    float p0 = pseudo[e * 3 + 0] * 4.f;
    float p1 = pseudo[e * 3 + 1] * 4.f;
    float p2 = pseudo[e * 3 + 2] * 4.f;
    float f0 = floorf(p0), f1 = floorf(p1), f2 = floorf(p2);
    float fr0 = p0 - f0, fr1 = p1 - f1, fr2 = p2 - f2;
    int lo0 = (int)f0; lo0 = lo0 < 0 ? 0 : (lo0 > 4 ? 4 : lo0);
    int lo1 = (int)f1; lo1 = lo1 < 0 ? 0 : (lo1 > 4 ? 4 : lo1);
    int lo2 = (int)f2; lo2 = lo2 < 0 ? 0 : (lo2 > 4 ? 4 : lo2);
    int hi0 = lo0 + 1 > 4 ? 4 : lo0 + 1;
    int hi1 = lo1 + 1 > 4 ? 4 : lo1 + 1;
    int hi2 = lo2 + 1 > 4 ? 4 : lo2 + 1;
#pragma unroll
    for (int s = 0; s < 8; ++s) {
        int c0 = (s >> 2) & 1, c1 = (s >> 1) & 1, c2 = s & 1;
        float b = (c0 ? fr0 : 1.f - fr0) * (c1 ? fr1 : 1.f - fr1) * (c2 ? fr2 : 1.f - fr2);
        int f = (c0 ? hi0 : lo0) + 5 * (c1 ? hi1 : lo1) + 25 * (c2 ? hi2 : lo2);
        bw[e * 8 + s] = b;
        fl[e * 8 + s] = f;
    }
}

// ---------------------------------------------------------------- degree
__global__ __launch_bounds__(256) void deg_kernel(const int* __restrict__ dst, int* __restrict__ degi)
{
    int e = blockIdx.x * 256 + threadIdx.x;
    if (e >= Ee) return;
    atomicAdd(&degi[dst[e]], 1);
}

__global__ __launch_bounds__(256) void invdeg_kernel(const int* __restrict__ degi, float* __restrict__ invdeg)
{
    int n = blockIdx.x * 256 + threadIdx.x;
    if (n >= Nn) return;
    int d = degi[n];
    invdeg[n] = 1.f / (float)(d > 0 ? d : 1);
}

// ---------------------------------------------------------------- pair sort (counting sort by (dstblock, k))
__global__ __launch_bounds__(256) void hist_kernel(const int* __restrict__ dst, const int* __restrict__ fl,
                                                   int* __restrict__ hist)
{
    int t = blockIdx.x * 256 + threadIdx.x;
    if (t >= Ee * 8) return;
    int e = t >> 3;
    int key = (dst[e] / NPB) * NKER + fl[t];
    atomicAdd(&hist[key], 1);
}

__global__ __launch_bounds__(1024) void scan_kernel(const int* __restrict__ hist, int* __restrict__ boff)
{
    const int T = 1024;
    const int per = (NBUCK + T - 1) / T;   // 31
    int t = threadIdx.x;
    int beg = t * per;
    int end = beg + per; if (end > NBUCK) end = NBUCK;
    int s = 0;
    for (int i = beg; i < end && i < NBUCK; ++i) s += hist[i];
    __shared__ int tmp[1024];
    tmp[t] = s;
    __syncthreads();
    for (int o2 = 1; o2 < 1024; o2 <<= 1) {
        int v = (t >= o2) ? tmp[t - o2] : 0;
        __syncthreads();
        tmp[t] += v;
        __syncthreads();
    }
    int run = tmp[t] - s;   // exclusive prefix for this thread's range
    for (int i = beg; i < end && i < NBUCK; ++i) { boff[i] = run; run += hist[i]; }
    if (t == T - 1) boff[NBUCK] = run;
}

__global__ __launch_bounds__(256) void fill_kernel(const int* __restrict__ srcA, const int* __restrict__ dstA,
                                                   const float* __restrict__ bw, const int* __restrict__ fl,
                                                   int* __restrict__ cursor, uint2* __restrict__ recs)
{
    int t = blockIdx.x * 256 + threadIdx.x;
    if (t >= Ee * 8) return;
    int e = t >> 3;
    int d = dstA[e];
    int key = (d / NPB) * NKER + fl[t];
    int pos = atomicAdd(&cursor[key], 1);
    unsigned meta = (unsigned)srcA[e] | ((unsigned)(d % NPB) << 16);
    recs[pos] = make_uint2(meta, __float_as_uint(bw[t]));
}

// ---------------------------------------------------------------- spline conv core
// grid (NBLK, ceil(125/KCHUNK)); one workgroup aggregates into its dst-block's LDS slab.
// Each wave takes a different k (wid-strided), so W[k] register loads amortize over
// the WHOLE bucket instead of 1/4 of it (4x less W traffic from L2).
template <int CIN, int COUT>
__global__ __launch_bounds__(256) void conv_pairs_kernel(const uint2* __restrict__ recs,
                                                         const int* __restrict__ boff,
                                                         const float* __restrict__ xin,
                                                         const float* __restrict__ W,
                                                         float* __restrict__ agg)
{
    __shared__ float aggl[NPB * COUT];
    const int blk = blockIdx.x;
    for (int idx = threadIdx.x; idx < NPB * COUT; idx += 256) aggl[idx] = 0.f;
    __syncthreads();

    const int lane = threadIdx.x & 63;
    const int wid  = threadIdx.x >> 6;
    const int o    = lane;

    int k0 = blockIdx.y * KCHUNK;
    int k1 = k0 + KCHUNK; if (k1 > NKER) k1 = NKER;

    for (int k = k0 + wid; k < k1; k += 4) {
        int bidx = blk * NKER + k;
        int pb = boff[bidx], pe = boff[bidx + 1];
        if (pb >= pe) continue;
        // register-resident W[k] column o
        float wreg[CIN];
#pragma unroll
        for (int i = 0; i < CIN; ++i)
            wreg[i] = (o < COUT) ? W[(k * CIN + i) * COUT + o] : 0.f;

        for (int p = pb; p < pe; ++p) {
            uint2 r = recs[p];
            unsigned meta = (unsigned)__builtin_amdgcn_readfirstlane((int)r.x);
            float wt = __uint_as_float(r.y);
            int src = (int)(meta & 0xFFFFu);
            int dl  = (int)(meta >> 16);
            const float* xs = xin + src * CIN;
            float m0 = 0.f, m1 = 0.f, m2 = 0.f, m3 = 0.f;
            if (CIN >= 4) {
#pragma unroll
                for (int i = 0; i < CIN; i += 4) {
                    m0 += xs[i + 0] * wreg[i + 0];
                    m1 += xs[i + 1] * wreg[i + 1];
                    m2 += xs[i + 2] * wreg[i + 2];
                    m3 += xs[i + 3] * wreg[i + 3];
                }
            } else {
#pragma unroll
                for (int i = 0; i < CIN; ++i) m0 += xs[i] * wreg[i];
            }
            float m = (m0 + m1) + (m2 + m3);
            if (o < COUT) atomicAdd(&aggl[dl * COUT + o], wt * m);
        }
    }
    __syncthreads();
    for (int idx = threadIdx.x; idx < NPB * COUT; idx += 256) {
        int n = blk * NPB + idx / COUT;
        if (n < Nn) atomicAdd(&agg[n * COUT + (idx % COUT)], aggl[idx]);
    }
}

// ---------------------------------------------------------------- conv epilogue: /deg + root + bias + elu
template <int CIN, int COUT>
__global__ __launch_bounds__(256) void epilogue_kernel(const float* __restrict__ agg,
                                                       const float* __restrict__ xin,
                                                       const float* __restrict__ root,
                                                       const float* __restrict__ bias,
                                                       const float* __restrict__ invdeg,
                                                       float* __restrict__ out)
{
    int idx = blockIdx.x * 256 + threadIdx.x;
    int n = idx / COUT, o = idx % COUT;
    if (n >= Nn) return;
    float r0 = 0.f, r1 = 0.f;
#pragma unroll
    for (int i = 0; i < CIN; i += 2) {
        r0 += xin[n * CIN + i] * root[i * COUT + o];
        if (CIN > 1) r1 += xin[n * CIN + i + 1] * root[(i + 1) * COUT + o];
    }
    float v = agg[n * COUT + o] * invdeg[n] + r0 + r1 + bias[o];
    out[n * COUT + o] = v > 0.f ? v : expm1f(v);
}

// ---------------------------------------------------------------- lin1: 64 -> 256, elu, emit bf16
__global__ __launch_bounds__(256) void lin1_kernel(const float* __restrict__ h,
                                                   const float* __restrict__ w1,
                                                   const float* __restrict__ b1,
                                                   __hip_bfloat16* __restrict__ out)
{
    int n = blockIdx.x;
    __shared__ float hl[64];
    if (threadIdx.x < 64) hl[threadIdx.x] = h[n * 64 + threadIdx.x];
    __syncthreads();
    int j = threadIdx.x;
    float a0 = b1[j], a1 = 0.f, a2 = 0.f, a3 = 0.f;
#pragma unroll
    for (int i = 0; i < 64; i += 4) {
        a0 += hl[i + 0] * w1[(i + 0) * 256 + j];
        a1 += hl[i + 1] * w1[(i + 1) * 256 + j];
        a2 += hl[i + 2] * w1[(i + 2) * 256 + j];
        a3 += hl[i + 3] * w1[(i + 3) * 256 + j];
    }
    float acc = (a0 + a1) + (a2 + a3);
    float v = acc > 0.f ? acc : expm1f(acc);
    out[(size_t)n * 256 + j] = __float2bfloat16(v);
}

// ---------------------------------------------------------------- w2 transpose + bf16 convert: [256][6890] f32 -> [6912][256] bf16
__global__ __launch_bounds__(256) void w2t_kernel(const float* __restrict__ w2,
                                                  __hip_bfloat16* __restrict__ w2t)
{
    __shared__ float t[32][33];
    int n0 = blockIdx.x * 32;       // class dim tile
    int k0 = blockIdx.y * 32;       // feature dim tile
    int tx = threadIdx.x & 31, ty = threadIdx.x >> 5;   // ty: 0..7
#pragma unroll
    for (int q = 0; q < 4; ++q) {
        int k = k0 + ty + 8 * q, n = n0 + tx;
        t[ty + 8 * q][tx] = (n < NCLS) ? w2[(size_t)k * NCLS + n] : 0.f;
    }
    __syncthreads();
#pragma unroll
    for (int q = 0; q < 4; ++q) {
        int n = n0 + ty + 8 * q;
        w2t[(size_t)n * 256 + k0 + tx] = __float2bfloat16(t[tx][ty + 8 * q]);
    }
}

// ---------------------------------------------------------------- lin2 via MFMA: [10000,256] @ [256,6890] + b2
// A: hbf [MPAD][256] bf16 row-major (zero-padded rows); B: w2t [NPAD][256] bf16 (zero-padded rows).
// Block: 4 waves in 2x2; wave tile 32(M) x 64(N); block tile 64 x 128.
__global__ __launch_bounds__(256) void lin2_mfma_kernel(const __hip_bfloat16* __restrict__ hbf,
                                                        const __hip_bfloat16* __restrict__ w2t,
                                                        const float* __restrict__ b2,
                                                        float* __restrict__ out)
{
    const int tid  = threadIdx.x;
    const int lane = tid & 63, wid = tid >> 6;
    const int wr = wid & 1, wc = wid >> 1;
    const int quad = lane >> 4, lq = lane & 15;

    const int mbase = blockIdx.x * 64 + wr * 32;
    const int nbase = blockIdx.y * 128 + wc * 64;

    f32x4 acc[2][4];
#pragma unroll
    for (int i = 0; i < 2; ++i)
#pragma unroll
        for (int j = 0; j < 4; ++j) acc[i][j] = (f32x4){0.f, 0.f, 0.f, 0.f};

    const unsigned short* A = (const unsigned short*)hbf;
    const unsigned short* B = (const unsigned short*)w2t;

    for (int kc = 0; kc < 256; kc += 32) {
        bf16x8 af[2], bfr[4];
#pragma unroll
        for (int mt = 0; mt < 2; ++mt)
            af[mt] = *(const bf16x8*)(A + (size_t)(mbase + mt * 16 + lq) * 256 + kc + quad * 8);
#pragma unroll
        for (int nt = 0; nt < 4; ++nt)
            bfr[nt] = *(const bf16x8*)(B + (size_t)(nbase + nt * 16 + lq) * 256 + kc + quad * 8);
#pragma unroll
        for (int mt = 0; mt < 2; ++mt)
#pragma unroll
            for (int nt = 0; nt < 4; ++nt)
                acc[mt][nt] = __builtin_amdgcn_mfma_f32_16x16x32_bf16(af[mt], bfr[nt], acc[mt][nt], 0, 0, 0);
    }

#pragma unroll
    for (int nt = 0; nt < 4; ++nt) {
        int col = nbase + nt * 16 + lq;
        if (col >= NCLS) continue;
        float bb = b2[col];
#pragma unroll
        for (int mt = 0; mt < 2; ++mt) {
#pragma unroll
            for (int r = 0; r < 4; ++r) {
                int row = mbase + mt * 16 + quad * 4 + r;
                if (row < Nn) out[(size_t)row * NCLS + col] = acc[mt][nt][r] + bb;
            }
        }
    }
}

// ---------------------------------------------------------------- log_softmax (in place over d_out rows)
__global__ __launch_bounds__(1024) void lsm_kernel(float* __restrict__ out)
{
    int row = blockIdx.x;
    float* p = out + (size_t)row * NCLS;
    __shared__ float red[16];
    int tid = threadIdx.x, lane = tid & 63, wid = tid >> 6;

    float m = -3.4e38f;
    for (int jj = tid; jj < NCLS; jj += 1024) m = fmaxf(m, p[jj]);
#pragma unroll
    for (int off = 32; off > 0; off >>= 1) m = fmaxf(m, __shfl_down(m, off));
    if (lane == 0) red[wid] = m;
    __syncthreads();
    if (tid == 0) {
        float mm = red[0];
        for (int w = 1; w < 16; ++w) mm = fmaxf(mm, red[w]);
        red[0] = mm;
    }
    __syncthreads();
    m = red[0];
    __syncthreads();

    float s = 0.f;
    for (int jj = tid; jj < NCLS; jj += 1024) s += expf(p[jj] - m);
#pragma unroll
    for (int off = 32; off > 0; off >>= 1) s += __shfl_down(s, off);
    if (lane == 0) red[wid] = s;
    __syncthreads();
    if (tid == 0) {
        float ss = 0.f;
        for (int w = 1; w < 16; ++w) ss += red[w];
        red[0] += ss;
    }
    __syncthreads();
    float lse = m + logf(red[0]);
    for (int jj = tid; jj < NCLS; jj += 1024) p[jj] -= lse;
}

// ---------------------------------------------------------------- launch
extern "C" void kernel_launch(void* const* d_in, const int* in_sizes, int n_in,
                              void* d_out, int out_size, void* d_ws, size_t ws_size,
                              hipStream_t stream)
{
    const float* x      = (const float*)d_in[0];
    const int*   ei     = (const int*)d_in[1];
    const float* pseudo = (const float*)d_in[2];
    const float* W1     = (const float*)d_in[3];
    const float* root1  = (const float*)d_in[4];
    const float* b1     = (const float*)d_in[5];
    const float* W2     = (const float*)d_in[6];
    const float* root2  = (const float*)d_in[7];
    const float* b2     = (const float*)d_in[8];
    const float* Ws     = (const float*)d_in[9];
    const float* roots  = (const float*)d_in[10];
    const float* bs     = (const float*)d_in[11];
    const float* l1w    = (const float*)d_in[12];
    const float* l1b    = (const float*)d_in[13];
    const float* l2w    = (const float*)d_in[14];
    const float* l2b    = (const float*)d_in[15];
    float* out = (float*)d_out;

    const int* srcA = ei;
    const int* dstA = ei + Ee;

    char* base = (char*)d_ws;
    size_t off = 0;
    auto carve = [&](size_t bytes) -> void* {
        void* p = base + off;
        off += (bytes + 255) & ~(size_t)255;
        return p;
    };
    float* bw     = (float*)carve((size_t)Ee * 8 * 4);
    int*   fl     = (int*)carve((size_t)Ee * 8 * 4);
    int*   hist   = (int*)carve((size_t)NBUCK * 4);
    int*   boff   = (int*)carve((size_t)(NBUCK + 1) * 4);
    int*   cursor = (int*)carve((size_t)NBUCK * 4);
    uint2* recs   = (uint2*)carve((size_t)Ee * 8 * 8);
    int*   degi   = (int*)carve((size_t)Nn * 4);
    float* invdeg = (float*)carve((size_t)Nn * 4);
    float* agg    = (float*)carve((size_t)Nn * 64 * 4);
    float* hA     = (float*)carve((size_t)Nn * 64 * 4);
    float* hB     = (float*)carve((size_t)Nn * 64 * 4);
    __hip_bfloat16* hbf = (__hip_bfloat16*)carve((size_t)MPAD * 256 * 2);
    __hip_bfloat16* w2t = (__hip_bfloat16*)carve((size_t)NPAD * 256 * 2);
    (void)ws_size; (void)n_in; (void)in_sizes; (void)out_size;

    hipMemsetAsync(hist, 0, (size_t)NBUCK * 4, stream);
    hipMemsetAsync(degi, 0, (size_t)Nn * 4, stream);
    hipMemsetAsync(hbf, 0, (size_t)MPAD * 256 * 2, stream);   // zero-pad rows >= Nn

    basis_kernel<<<(Ee + 255) / 256, 256, 0, stream>>>(pseudo, bw, fl);
    deg_kernel<<<(Ee + 255) / 256, 256, 0, stream>>>(dstA, degi);
    invdeg_kernel<<<(Nn + 255) / 256, 256, 0, stream>>>(degi, invdeg);
    hist_kernel<<<(Ee * 8 + 255) / 256, 256, 0, stream>>>(dstA, fl, hist);
    scan_kernel<<<1, 1024, 0, stream>>>(hist, boff);
    hipMemcpyAsync(cursor, boff, (size_t)NBUCK * 4, hipMemcpyDeviceToDevice, stream);
    fill_kernel<<<(Ee * 8 + 255) / 256, 256, 0, stream>>>(srcA, dstA, bw, fl, cursor, recs);
    w2t_kernel<<<dim3((NPAD + 31) / 32, 8), 256, 0, stream>>>(l2w, w2t);

    const dim3 cgrid(NBLK, (NKER + KCHUNK - 1) / KCHUNK);

    // layer 1: 1 -> 32
    hipMemsetAsync(agg, 0, (size_t)Nn * 64 * 4, stream);
    conv_pairs_kernel<1, 32><<<cgrid, 256, 0, stream>>>(recs, boff, x, W1, agg);
    epilogue_kernel<1, 32><<<(Nn * 32 + 255) / 256, 256, 0, stream>>>(agg, x, root1, b1, invdeg, hA);

    // layer 2: 32 -> 64
    hipMemsetAsync(agg, 0, (size_t)Nn * 64 * 4, stream);
    conv_pairs_kernel<32, 64><<<cgrid, 256, 0, stream>>>(recs, boff, hA, W2, agg);
    epilogue_kernel<32, 64><<<(Nn * 64 + 255) / 256, 256, 0, stream>>>(agg, hA, root2, b2, invdeg, hB);

    // layers 3..6: 64 -> 64
    float* cin = hB;
    float* cot = hA;
    for (int l = 0; l < 4; ++l) {
        hipMemsetAsync(agg, 0, (size_t)Nn * 64 * 4, stream);
        conv_pairs_kernel<64, 64><<<cgrid, 256, 0, stream>>>(recs, boff, cin, Ws + (size_t)l * 125 * 64 * 64, agg);
        epilogue_kernel<64, 64><<<(Nn * 64 + 255) / 256, 256, 0, stream>>>(
            agg, cin, roots + (size_t)l * 64 * 64, bs + (size_t)l * 64, invdeg, cot);
        float* t = cin; cin = cot; cot = t;
    }

    lin1_kernel<<<Nn, 256, 0, stream>>>(cin, l1w, l1b, hbf);
    lin2_mfma_kernel<<<dim3(MPAD / 64, NPAD / 128), 256, 0, stream>>>(hbf, w2t, l2b, out);
    lsm_kernel<<<Nn, 1024, 0, stream>>>(out);
}